// Round 23
// baseline (2153.966 us; speedup 1.0000x reference)
//
#include <hip/hip_runtime.h>

constexpr int B_ = 64, I_ = 256, H_ = 512, T_ = 512;
constexpr int BH_ = B_ * H_;

// d_ws layout: [0,256KB) hbuf ping-pong (TAGGED f32 h) | [512KB,+16.8MB) xT (f16)
constexpr size_t WS_XT_OFF = 524288;

typedef float f32x4 __attribute__((ext_vector_type(4)));
typedef _Float16 h2 __attribute__((ext_vector_type(2)));
typedef _Float16 h8v __attribute__((ext_vector_type(8)));
union H8 { h8v v; h2 p[4]; };

#if defined(__has_builtin)
#if __has_builtin(__builtin_amdgcn_fdot2)
#define HAVE_FDOT2 1
#endif
#endif

__device__ __forceinline__ float dot2(h2 a, h2 b, float c) {
#ifdef HAVE_FDOT2
    return __builtin_amdgcn_fdot2(a, b, c, false);
#else
    return c + (float)a[0] * (float)b[0] + (float)a[1] * (float)b[1];
#endif
}

__device__ __forceinline__ float sigm(float v) { return 1.0f / (1.0f + __expf(-v)); }
__device__ __forceinline__ float tanh_fast(float v) {
    float e = __expf(2.0f * v);          // overflow->inf->1, underflow->0->-1: both exact
    return 1.0f - 2.0f / (e + 1.0f);
}

// x (B,I,T) f32 -> xT (T,B,I) f16, one-time
__global__ __launch_bounds__(256)
void transpose_x(const float* __restrict__ x, _Float16* __restrict__ xT)
{
    __shared__ float tile[32][33];
    const int b  = blockIdx.z;
    const int i0 = blockIdx.y << 5;
    const int t0 = blockIdx.x << 5;
    const int lt = threadIdx.x;
    const int li = threadIdx.y;
#pragma unroll
    for (int r = 0; r < 4; ++r) {
        int i = li + (r << 3);
        tile[i][lt] = x[((size_t)b * I_ + (i0 + i)) * T_ + (t0 + lt)];
    }
    __syncthreads();
#pragma unroll
    for (int r = 0; r < 4; ++r) {
        int tt = li + (r << 3);
        xT[((size_t)(t0 + tt) * B_ + b) * I_ + (i0 + lt)] = (_Float16)tile[lt][tt];
    }
}

__global__ __launch_bounds__(512, 1)
void lstm_fused(const _Float16* __restrict__ xT,
                const float* __restrict__ Wih,
                const float* __restrict__ Whh,
                const float* __restrict__ bih,
                const float* __restrict__ bhh,
                const float* __restrict__ h0,
                const float* __restrict__ c0,
                float* __restrict__ out,
                float* __restrict__ hbuf)
{
    // arena 51456B: redA[16][133] f32x4 (34048, single-phase) | actx2 h2 2x(8x132)
    // (8448, DOUBLE-buffered) | acth2 h2 8x264 (8448) | hsh f32[128] (512)
    __shared__ __align__(16) char smem[51456];
    f32x4* redA  = (f32x4*)smem;
    h2*    actx2 = (h2*)(smem + 34048);               // [buf*1056 + row*132 + k2]
    h2*    acth2 = (h2*)(smem + 34048 + 8448);        // row stride 264 h2
    float* hsh   = (float*)(smem + 34048 + 8448 + 8448);

    const int tid  = threadIdx.x;
    const int wv   = tid >> 6;
    const int lane = tid & 63;
    const int jl   = lane & 15;                  // j within block's 16
    const int slq  = lane >> 4;                  // 0..3
    const int bg   = wv >> 2;                    // batch group 0..1 (4 batches)
    const int sl16 = ((wv & 3) << 2) | slq;      // k-slice 0..15 (48 f32: 16 x + 32 h)

    const int blk = blockIdx.x;
    const int bt  = blk >> 5;
    const int jt  = blk & 31;
    const int b0  = bt << 3;
    const int j0  = jt << 4;

    // ---- weights packed h2 in registers: x k=[sl16*16,+16), h k=[sl16*32,+32) ----
    const int j = j0 + jl;
    h2 wx2[4][8];
    h2 wh2[4][16];
#pragma unroll
    for (int g = 0; g < 4; ++g) {
        const size_t row = (size_t)(g * H_ + j);
#pragma unroll
        for (int q = 0; q < 8; ++q) {
            wx2[g][q][0] = (_Float16)Wih[row * I_ + (sl16 << 4) + 2 * q];
            wx2[g][q][1] = (_Float16)Wih[row * I_ + (sl16 << 4) + 2 * q + 1];
        }
#pragma unroll
        for (int q = 0; q < 16; ++q) {
            wh2[g][q][0] = (_Float16)Whh[row * H_ + (sl16 << 5) + 2 * q];
            wh2[g][q][1] = (_Float16)Whh[row * H_ + (sl16 << 5) + 2 * q + 1];
        }
    }

    // finalizer (tid<128) per-(b,j) state
    const int fb = b0 + (tid >> 4);
    const int fj = j0 + (tid & 15);
    float c = 0.f;
    f32x4 bias4 = {0.f, 0.f, 0.f, 0.f};
    if (tid < 128) {
        c = c0[(size_t)fb * H_ + fj];
#pragma unroll
        for (int g = 0; g < 4; ++g) bias4[g] = bih[g * H_ + fj] + bhh[g * H_ + fj];
    }

    float* enc = out + BH_;

    // h-stage role: batch sb, f32 offset hb_off — covers exactly this wave's h-FMA window
    const int sb     = (bg << 2) + (lane >> 4);
    const int hb_off = ((wv & 3) << 7) + ((lane & 15) << 3);
    h2* hdst = acth2 + sb * 264 + (hb_off >> 1);

    // ---- prologue: commit x(0) to buf0, prefetch x(1) ----
    uint2 xv;
    {
        uint2 x0 = *(const uint2*)(xT + (size_t)b0 * I_ + tid * 4);
        *(uint2*)((char*)(actx2 + (size_t)(tid >> 6) * 132) + (size_t)(tid & 63) * 8) = x0;
        xv = *(const uint2*)(xT + ((size_t)B_ + (size_t)b0) * I_ + tid * 4);
    }
    __syncthreads();

    for (int t = 0; t < T_; ++t) {
        const h2* actxb = actx2 + (size_t)(t & 1) * 1056;

        // ---- (1) issue tag-poll loads FIRST (no wait; RTT overlaps x-FMA) ----
        f32x4 v0, v1;
        const float* hsrc = hbuf + (size_t)((t - 1) & 1) * BH_
                          + (size_t)(b0 + sb) * H_ + hb_off;
        if (t > 0) {
            asm volatile("global_load_dwordx4 %0, %2, off sc0 sc1\n\t"
                         "global_load_dwordx4 %1, %3, off sc0 sc1"
                         : "=&v"(v0), "=&v"(v1) : "v"(hsrc), "v"(hsrc + 4));
            __builtin_amdgcn_sched_barrier(0);
        }

        // ---- (2) FMA x-part: 4 batches x 4 gates x 8 dot2 ----
        f32x4 r4[4];
#pragma unroll
        for (int i = 0; i < 4; ++i) {
            const int bq = (bg << 2) + i;
            H8 ax0, ax1;
            ax0.v = *(const h8v*)(actxb + (size_t)bq * 132 + (sl16 << 3));
            ax1.v = *(const h8v*)(actxb + (size_t)bq * 132 + (sl16 << 3) + 4);
            float s0 = 0.f, s1 = 0.f, s2 = 0.f, s3 = 0.f;
#pragma unroll
            for (int q = 0; q < 4; ++q) {
                s0 = dot2(ax0.p[q], wx2[0][q], s0);
                s1 = dot2(ax0.p[q], wx2[1][q], s1);
                s2 = dot2(ax0.p[q], wx2[2][q], s2);
                s3 = dot2(ax0.p[q], wx2[3][q], s3);
            }
#pragma unroll
            for (int q = 0; q < 4; ++q) {
                s0 = dot2(ax1.p[q], wx2[0][q + 4], s0);
                s1 = dot2(ax1.p[q], wx2[1][q + 4], s1);
                s2 = dot2(ax1.p[q], wx2[2][q + 4], s2);
                s3 = dot2(ax1.p[q], wx2[3][q + 4], s3);
            }
            r4[i] = (f32x4){s0, s1, s2, s3};
        }

        // ---- (3) wait, tag-check (eager first retries), detag, stage to LDS f16 ----
        if (t > 0) {
            asm volatile("s_waitcnt vmcnt(0)" ::: "memory");
            __builtin_amdgcn_sched_barrier(0);
            const float Kc = 2.0f + 2.0f * (float)(((t - 1) >> 1) & 1);
            bool ok = true;
#pragma unroll
            for (int e = 0; e < 4; ++e) {
                ok = ok && (fabsf(v0[e] - Kc) < 0.75f);
                ok = ok && (fabsf(v1[e] - Kc) < 0.75f);
            }
            for (unsigned it = 0; !ok && it < 32768u; ++it) {
                if (it >= 2) __builtin_amdgcn_s_sleep(1);   // first 2 retries sleep-free
                asm volatile("global_load_dwordx4 %0, %2, off sc0 sc1\n\t"
                             "global_load_dwordx4 %1, %3, off sc0 sc1\n\t"
                             "s_waitcnt vmcnt(0)"
                             : "=&v"(v0), "=&v"(v1) : "v"(hsrc), "v"(hsrc + 4) : "memory");
                ok = true;
#pragma unroll
                for (int e = 0; e < 4; ++e) {
                    ok = ok && (fabsf(v0[e] - Kc) < 0.75f);
                    ok = ok && (fabsf(v1[e] - Kc) < 0.75f);
                }
            }
            v0 = (v0 - Kc) * 2.0f;                        // detag (exact to 2^-22)
            v1 = (v1 - Kc) * 2.0f;
        } else {
            const float* src = h0 + (size_t)(b0 + sb) * H_ + hb_off;
            v0 = *(const f32x4*)src;
            v1 = *(const f32x4*)(src + 4);
        }
        {
            H8 hv;
#pragma unroll
            for (int e = 0; e < 2; ++e) { hv.p[e][0]   = (_Float16)v0[2*e];
                                          hv.p[e][1]   = (_Float16)v0[2*e+1];
                                          hv.p[e+2][0] = (_Float16)v1[2*e];
                                          hv.p[e+2][1] = (_Float16)v1[2*e+1]; }
            *(h8v*)hdst = hv.v;
            asm volatile("s_waitcnt lgkmcnt(0)" ::: "memory");  // wave-local visibility
            __builtin_amdgcn_sched_barrier(0);
        }

        // ---- (4) FMA h-part: 4 batches x 4 gates x 16 dot2 (wave-private windows) ----
#pragma unroll
        for (int i = 0; i < 4; ++i) {
            const int bq = (bg << 2) + i;
            const h2* hrow = acth2 + (size_t)bq * 264 + (sl16 << 4);
            H8 a0, a1, a2, a3;
            a0.v = *(const h8v*)(hrow);
            a1.v = *(const h8v*)(hrow + 4);
            a2.v = *(const h8v*)(hrow + 8);
            a3.v = *(const h8v*)(hrow + 12);
            float s0 = r4[i][0], s1 = r4[i][1], s2 = r4[i][2], s3 = r4[i][3];
#pragma unroll
            for (int q = 0; q < 4; ++q) {
                s0 = dot2(a0.p[q], wh2[0][q], s0);
                s1 = dot2(a0.p[q], wh2[1][q], s1);
                s2 = dot2(a0.p[q], wh2[2][q], s2);
                s3 = dot2(a0.p[q], wh2[3][q], s3);
            }
#pragma unroll
            for (int q = 0; q < 4; ++q) {
                s0 = dot2(a1.p[q], wh2[0][q + 4], s0);
                s1 = dot2(a1.p[q], wh2[1][q + 4], s1);
                s2 = dot2(a1.p[q], wh2[2][q + 4], s2);
                s3 = dot2(a1.p[q], wh2[3][q + 4], s3);
            }
#pragma unroll
            for (int q = 0; q < 4; ++q) {
                s0 = dot2(a2.p[q], wh2[0][q + 8], s0);
                s1 = dot2(a2.p[q], wh2[1][q + 8], s1);
                s2 = dot2(a2.p[q], wh2[2][q + 8], s2);
                s3 = dot2(a2.p[q], wh2[3][q + 8], s3);
            }
#pragma unroll
            for (int q = 0; q < 4; ++q) {
                s0 = dot2(a3.p[q], wh2[0][q + 12], s0);
                s1 = dot2(a3.p[q], wh2[1][q + 12], s1);
                s2 = dot2(a3.p[q], wh2[2][q + 12], s2);
                s3 = dot2(a3.p[q], wh2[3][q + 12], s3);
            }
            r4[i] = (f32x4){s0, s1, s2, s3};
        }

        // ---- (5) commit x(t+1) to the OTHER buffer; prefetch x(t+2) ----
        // (write separated from all reads by barrier B; removes barrier A entirely)
        if (t + 1 < T_) {
            *(uint2*)((char*)(actx2 + (size_t)((t + 1) & 1) * 1056
                              + (size_t)(tid >> 6) * 132) + (size_t)(tid & 63) * 8) = xv;
            if (t + 2 < T_)
                xv = *(const uint2*)(xT + ((size_t)(t + 2) * B_ + b0) * I_ + tid * 4);
        }

        // ---- (6) single-phase partial write ----
#pragma unroll
        for (int i = 0; i < 4; ++i)
            redA[sl16 * 133 + (((bg << 2) + i) << 4) + jl] = r4[i];
        __syncthreads();                                   // B: the ONLY barrier/step

        // ---- (7) finalize + fused publish (publish-first), waves 0-1 only ----
        // Safety of barrier-A removal: any wave's step-t+1 redA write requires its
        // h(t) poll to hit => publishes (issued AFTER these redA reads) + IF RTT +
        // h-FMA  => >=0.9us separation from the reads below.
        if (tid < 128) {
            f32x4 G = bias4;
#pragma unroll
            for (int s = 0; s < 16; ++s) G += redA[s * 133 + tid];
            float ig = sigm(G[0]), fg = sigm(G[1]);
            float gg = tanh_fast(G[2]);
            float og = sigm(G[3]);
            c = fg * c + ig * gg;
            float hv = og * tanh_fast(c);
            hsh[tid] = hv;
            if (t == T_ - 1) {
                enc[((size_t)fb * H_ + fj) * T_ + t] = hv;
                out[(size_t)fb * H_ + fj] = hv;
            } else {
                asm volatile("s_waitcnt lgkmcnt(0)" ::: "memory");  // own-wave hsh visible
                __builtin_amdgcn_sched_barrier(0);
                if (lane < 16) {                            // publish FIRST
                    const float Kp = 2.0f + 2.0f * (float)((t >> 1) & 1);
                    f32x4 v = *(const f32x4*)(&hsh[(wv << 6) + ((lane >> 2) << 4) + ((lane & 3) << 2)]);
                    v = v * 0.5f + Kp;                      // tag-bias
                    float* dst = hbuf + (size_t)(t & 1) * BH_
                               + (size_t)(b0 + (wv << 2) + (lane >> 2)) * H_
                               + j0 + ((lane & 3) << 2);
                    asm volatile("global_store_dwordx4 %0, %1, off sc0 sc1"
                                 :: "v"(dst), "v"(v) : "memory");   // fire-and-forget
                }
                enc[((size_t)fb * H_ + fj) * T_ + t] = hv;  // cached store, after publish
            }
        }
        // WAW safety: each thread's own step-t+1 tag-poll issues s_waitcnt vmcnt(0),
        // draining these stores long before the slot is rewritten at t+2.
    }
}

extern "C" void kernel_launch(void* const* d_in, const int* in_sizes, int n_in,
                              void* d_out, int out_size, void* d_ws, size_t ws_size,
                              hipStream_t stream)
{
    (void)in_sizes; (void)n_in; (void)out_size; (void)ws_size;
    const float* x   = (const float*)d_in[0];
    const float* Wih = (const float*)d_in[1];
    const float* Whh = (const float*)d_in[2];
    const float* bih = (const float*)d_in[3];
    const float* bhh = (const float*)d_in[4];
    const float* h0  = (const float*)d_in[5];
    const float* c0  = (const float*)d_in[6];
    float* out  = (float*)d_out;
    float* hbuf = (float*)d_ws;
    _Float16* xT = (_Float16*)((char*)d_ws + WS_XT_OFF);

    // zero hbuf every launch: stale tags from a previous replay must not validate
    hipMemsetAsync(d_ws, 0, 2 * BH_ * sizeof(float), stream);
    transpose_x<<<dim3(T_ / 32, I_ / 32, B_), dim3(32, 8), 0, stream>>>(x, xT);

    void* args[] = { (void*)&xT, (void*)&Wih, (void*)&Whh, (void*)&bih,
                     (void*)&bhh, (void*)&h0, (void*)&c0, (void*)&out, (void*)&hbuf };
    hipLaunchCooperativeKernel((void*)lstm_fused, dim3(256), dim3(512), args, 0, stream);
}

// Round 24
// 1648.021 us; speedup vs baseline: 1.3070x; 1.3070x over previous
//
#include <hip/hip_runtime.h>

constexpr int B_ = 64, I_ = 256, H_ = 512, T_ = 512;
constexpr int BH_ = B_ * H_;

// d_ws layout: [0,256KB) hbuf ping-pong (TAGGED f32 h) | [512KB,+16.8MB) xT (f16)
constexpr size_t WS_XT_OFF = 524288;

typedef float f32x4 __attribute__((ext_vector_type(4)));
typedef _Float16 h2 __attribute__((ext_vector_type(2)));
typedef _Float16 h8v __attribute__((ext_vector_type(8)));
union H8 { h8v v; h2 p[4]; };

#if defined(__has_builtin)
#if __has_builtin(__builtin_amdgcn_fdot2)
#define HAVE_FDOT2 1
#endif
#endif

__device__ __forceinline__ float dot2(h2 a, h2 b, float c) {
#ifdef HAVE_FDOT2
    return __builtin_amdgcn_fdot2(a, b, c, false);
#else
    return c + (float)a[0] * (float)b[0] + (float)a[1] * (float)b[1];
#endif
}

__device__ __forceinline__ float sigm(float v) { return 1.0f / (1.0f + __expf(-v)); }
__device__ __forceinline__ float tanh_fast(float v) {
    float e = __expf(2.0f * v);          // overflow->inf->1, underflow->0->-1: both exact
    return 1.0f - 2.0f / (e + 1.0f);
}

// x (B,I,T) f32 -> xT (T,B,I) f16, one-time
__global__ __launch_bounds__(256)
void transpose_x(const float* __restrict__ x, _Float16* __restrict__ xT)
{
    __shared__ float tile[32][33];
    const int b  = blockIdx.z;
    const int i0 = blockIdx.y << 5;
    const int t0 = blockIdx.x << 5;
    const int lt = threadIdx.x;      // 0..31
    const int li = threadIdx.y;      // 0..7
#pragma unroll
    for (int r = 0; r < 4; ++r) {
        int i = li + (r << 3);
        tile[i][lt] = x[((size_t)b * I_ + (i0 + i)) * T_ + (t0 + lt)];
    }
    __syncthreads();
#pragma unroll
    for (int r = 0; r < 4; ++r) {
        int tt = li + (r << 3);
        xT[((size_t)(t0 + tt) * B_ + b) * I_ + (i0 + lt)] = (_Float16)tile[lt][tt];
    }
}

__global__ __launch_bounds__(512, 1)
void lstm_fused(const float* __restrict__ x,
                const _Float16* __restrict__ xT,   // nullptr -> strided fallback
                const float* __restrict__ Wih,
                const float* __restrict__ Whh,
                const float* __restrict__ bih,
                const float* __restrict__ bhh,
                const float* __restrict__ h0,
                const float* __restrict__ c0,
                float* __restrict__ out,
                float* __restrict__ hbuf)
{
    // arena 47232B: redA[16][133] f32x4 (34048, SINGLE-phase) | actx2 h2 8x132
    // (4224) | acth2 h2 8x264 (8448) | hsh f32[128] (512)
    __shared__ __align__(16) char smem[47232];
    f32x4* redA  = (f32x4*)smem;
    h2*    actx2 = (h2*)(smem + 34048);               // row stride 132 h2 (528B)
    h2*    acth2 = (h2*)(smem + 34048 + 4224);        // row stride 264 h2 (1056B)
    float* hsh   = (float*)(smem + 34048 + 4224 + 8448);

    const int tid  = threadIdx.x;
    const int wv   = tid >> 6;
    const int lane = tid & 63;
    const int jl   = lane & 15;                  // j within block's 16
    const int slq  = lane >> 4;                  // 0..3
    const int bg   = wv >> 2;                    // batch group 0..1 (4 batches)
    const int sl16 = ((wv & 3) << 2) | slq;      // k-slice 0..15 (48 f32: 16 x + 32 h)

    const int blk = blockIdx.x;
    const int bt  = blk >> 5;
    const int jt  = blk & 31;
    const int b0  = bt << 3;
    const int j0  = jt << 4;

    // ---- weights packed h2 in registers: x k=[sl16*16,+16), h k=[sl16*32,+32) ----
    const int j = j0 + jl;
    h2 wx2[4][8];
    h2 wh2[4][16];
#pragma unroll
    for (int g = 0; g < 4; ++g) {
        const size_t row = (size_t)(g * H_ + j);
#pragma unroll
        for (int q = 0; q < 8; ++q) {
            wx2[g][q][0] = (_Float16)Wih[row * I_ + (sl16 << 4) + 2 * q];
            wx2[g][q][1] = (_Float16)Wih[row * I_ + (sl16 << 4) + 2 * q + 1];
        }
#pragma unroll
        for (int q = 0; q < 16; ++q) {
            wh2[g][q][0] = (_Float16)Whh[row * H_ + (sl16 << 5) + 2 * q];
            wh2[g][q][1] = (_Float16)Whh[row * H_ + (sl16 << 5) + 2 * q + 1];
        }
    }

    // finalizer (tid<128) per-(b,j) state
    const int fb = b0 + (tid >> 4);
    const int fj = j0 + (tid & 15);
    float c = 0.f;
    f32x4 bias4 = {0.f, 0.f, 0.f, 0.f};
    if (tid < 128) {
        c = c0[(size_t)fb * H_ + fj];
#pragma unroll
        for (int g = 0; g < 4; ++g) bias4[g] = bih[g * H_ + fj] + bhh[g * H_ + fj];
    }

    float* enc = out + BH_;

    // h-stage role: batch sb, f32 offset hb_off — covers exactly this wave's h-FMA window
    const int sb     = (bg << 2) + (lane >> 4);            // batch 0..7
    const int hb_off = ((wv & 3) << 7) + ((lane & 15) << 3); // f32 offset, mult of 8
    h2* hdst = acth2 + sb * 264 + (hb_off >> 1);

    // prologue: prefetch x slab for t=0 (4 halves = 8B per thread)
    uint2 xv;
    if (xT) xv = *(const uint2*)(xT + (size_t)b0 * I_ + tid * 4);

    for (int t = 0; t < T_; ++t) {
        // ---- (1) commit x(t) ----
        if (xT) {
            *(uint2*)((char*)(actx2 + (size_t)(tid >> 6) * 132) + (size_t)(tid & 63) * 8) = xv;
        } else {
#pragma unroll
            for (int r = 0; r < 4; ++r) {
                int flat = tid + (r << 9), bb = flat >> 8, ii = flat & 255;
                ((_Float16*)(actx2 + (size_t)bb * 132))[ii] =
                    (_Float16)x[((size_t)(b0 + bb) * I_ + ii) * T_ + t];
            }
        }
        __syncthreads();                                   // A: actx ready; redA(t-1) reads done

        // ---- (2) issue tag-poll loads EARLY (no wait) ----
        f32x4 v0, v1;
        const float* hsrc = hbuf + (size_t)((t - 1) & 1) * BH_
                          + (size_t)(b0 + sb) * H_ + hb_off;
        if (t > 0) {
            asm volatile("global_load_dwordx4 %0, %2, off sc0 sc1\n\t"
                         "global_load_dwordx4 %1, %3, off sc0 sc1"
                         : "=&v"(v0), "=&v"(v1) : "v"(hsrc), "v"(hsrc + 4));
            __builtin_amdgcn_sched_barrier(0);             // pin: loads issue before x-FMA
        }

        // ---- (3) FMA x-part: 4 batches x 4 gates x 8 dot2 (overlaps poll RTT) ----
        f32x4 r4[4];
#pragma unroll
        for (int i = 0; i < 4; ++i) {
            const int bq = (bg << 2) + i;
            H8 ax0, ax1;
            ax0.v = *(const h8v*)(actx2 + (size_t)bq * 132 + (sl16 << 3));
            ax1.v = *(const h8v*)(actx2 + (size_t)bq * 132 + (sl16 << 3) + 4);
            float s0 = 0.f, s1 = 0.f, s2 = 0.f, s3 = 0.f;
#pragma unroll
            for (int q = 0; q < 4; ++q) {
                s0 = dot2(ax0.p[q], wx2[0][q], s0);
                s1 = dot2(ax0.p[q], wx2[1][q], s1);
                s2 = dot2(ax0.p[q], wx2[2][q], s2);
                s3 = dot2(ax0.p[q], wx2[3][q], s3);
            }
#pragma unroll
            for (int q = 0; q < 4; ++q) {
                s0 = dot2(ax1.p[q], wx2[0][q + 4], s0);
                s1 = dot2(ax1.p[q], wx2[1][q + 4], s1);
                s2 = dot2(ax1.p[q], wx2[2][q + 4], s2);
                s3 = dot2(ax1.p[q], wx2[3][q + 4], s3);
            }
            r4[i] = (f32x4){s0, s1, s2, s3};
        }

        // ---- (4) wait, tag-check (retry on miss), detag, stage to LDS f16 ----
        if (t > 0) {
            asm volatile("s_waitcnt vmcnt(0)" ::: "memory");
            __builtin_amdgcn_sched_barrier(0);
            const float Kc = 2.0f + 2.0f * (float)(((t - 1) >> 1) & 1);
            bool ok = true;
#pragma unroll
            for (int e = 0; e < 4; ++e) {
                ok = ok && (fabsf(v0[e] - Kc) < 0.75f);
                ok = ok && (fabsf(v1[e] - Kc) < 0.75f);
            }
            for (unsigned it = 0; !ok && it < 32768u; ++it) {
                __builtin_amdgcn_s_sleep(1);
                asm volatile("global_load_dwordx4 %0, %2, off sc0 sc1\n\t"
                             "global_load_dwordx4 %1, %3, off sc0 sc1\n\t"
                             "s_waitcnt vmcnt(0)"
                             : "=&v"(v0), "=&v"(v1) : "v"(hsrc), "v"(hsrc + 4) : "memory");
                ok = true;
#pragma unroll
                for (int e = 0; e < 4; ++e) {
                    ok = ok && (fabsf(v0[e] - Kc) < 0.75f);
                    ok = ok && (fabsf(v1[e] - Kc) < 0.75f);
                }
            }
            v0 = (v0 - Kc) * 2.0f;                        // detag (exact to 2^-22)
            v1 = (v1 - Kc) * 2.0f;
        } else {
            const float* src = h0 + (size_t)(b0 + sb) * H_ + hb_off;
            v0 = *(const f32x4*)src;
            v1 = *(const f32x4*)(src + 4);
        }
        {
            H8 hv;
#pragma unroll
            for (int e = 0; e < 2; ++e) { hv.p[e][0]   = (_Float16)v0[2*e];
                                          hv.p[e][1]   = (_Float16)v0[2*e+1];
                                          hv.p[e+2][0] = (_Float16)v1[2*e];
                                          hv.p[e+2][1] = (_Float16)v1[2*e+1]; }
            *(h8v*)hdst = hv.v;
            asm volatile("s_waitcnt lgkmcnt(0)" ::: "memory");  // wave-local visibility
            __builtin_amdgcn_sched_barrier(0);
        }

        // ---- (5) prefetch x(t+1) ----
        if (xT && t + 1 < T_)
            xv = *(const uint2*)(xT + ((size_t)(t + 1) * B_ + b0) * I_ + tid * 4);

        // ---- (6) FMA h-part: 4 batches x 4 gates x 16 dot2 (wave-private windows) ----
#pragma unroll
        for (int i = 0; i < 4; ++i) {
            const int bq = (bg << 2) + i;
            const h2* hrow = acth2 + (size_t)bq * 264 + (sl16 << 4);
            H8 a0, a1, a2, a3;
            a0.v = *(const h8v*)(hrow);
            a1.v = *(const h8v*)(hrow + 4);
            a2.v = *(const h8v*)(hrow + 8);
            a3.v = *(const h8v*)(hrow + 12);
            float s0 = r4[i][0], s1 = r4[i][1], s2 = r4[i][2], s3 = r4[i][3];
#pragma unroll
            for (int q = 0; q < 4; ++q) {
                s0 = dot2(a0.p[q], wh2[0][q], s0);
                s1 = dot2(a0.p[q], wh2[1][q], s1);
                s2 = dot2(a0.p[q], wh2[2][q], s2);
                s3 = dot2(a0.p[q], wh2[3][q], s3);
            }
#pragma unroll
            for (int q = 0; q < 4; ++q) {
                s0 = dot2(a1.p[q], wh2[0][q + 4], s0);
                s1 = dot2(a1.p[q], wh2[1][q + 4], s1);
                s2 = dot2(a1.p[q], wh2[2][q + 4], s2);
                s3 = dot2(a1.p[q], wh2[3][q + 4], s3);
            }
#pragma unroll
            for (int q = 0; q < 4; ++q) {
                s0 = dot2(a2.p[q], wh2[0][q + 8], s0);
                s1 = dot2(a2.p[q], wh2[1][q + 8], s1);
                s2 = dot2(a2.p[q], wh2[2][q + 8], s2);
                s3 = dot2(a2.p[q], wh2[3][q + 8], s3);
            }
#pragma unroll
            for (int q = 0; q < 4; ++q) {
                s0 = dot2(a3.p[q], wh2[0][q + 12], s0);
                s1 = dot2(a3.p[q], wh2[1][q + 12], s1);
                s2 = dot2(a3.p[q], wh2[2][q + 12], s2);
                s3 = dot2(a3.p[q], wh2[3][q + 12], s3);
            }
            r4[i] = (f32x4){s0, s1, s2, s3};
        }

        // ---- (7) SINGLE-phase partial write ----
#pragma unroll
        for (int i = 0; i < 4; ++i)
            redA[sl16 * 133 + (((bg << 2) + i) << 4) + jl] = r4[i];
        __syncthreads();                                   // B: redA complete

        // ---- (8) finalize + FUSED publish (waves 0-1 only; no extra barrier) ----
        if (tid < 128) {
            f32x4 G = bias4;
#pragma unroll
            for (int s = 0; s < 16; ++s) G += redA[s * 133 + tid];
            float ig = sigm(G[0]), fg = sigm(G[1]);
            float gg = tanh_fast(G[2]);
            float og = sigm(G[3]);
            c = fg * c + ig * gg;
            float hv = og * tanh_fast(c);
            hsh[tid] = hv;                                 // wave-private half
            enc[((size_t)fb * H_ + fj) * T_ + t] = hv;     // plain cached store
            if (t == T_ - 1) {
                out[(size_t)fb * H_ + fj] = hv;            // final hidden (1,B,H)
            } else {
                asm volatile("s_waitcnt lgkmcnt(0)" ::: "memory");  // own-wave hsh visible
                __builtin_amdgcn_sched_barrier(0);
                if (lane < 16) {
                    const float Kp = 2.0f + 2.0f * (float)((t >> 1) & 1);
                    f32x4 v = *(const f32x4*)(&hsh[(wv << 6) + ((lane >> 2) << 4) + ((lane & 3) << 2)]);
                    v = v * 0.5f + Kp;                     // tag-bias
                    float* dst = hbuf + (size_t)(t & 1) * BH_
                               + (size_t)(b0 + (wv << 2) + (lane >> 2)) * H_
                               + j0 + ((lane & 3) << 2);
                    asm volatile("global_store_dwordx4 %0, %1, off sc0 sc1"
                                 :: "v"(dst), "v"(v) : "memory");   // fire-and-forget
                }
            }
        }
        // WAW safety: each thread's own step-t+1 tag-poll issues s_waitcnt vmcnt(0),
        // draining these stores long before the slot is rewritten at t+2.
    }
}

extern "C" void kernel_launch(void* const* d_in, const int* in_sizes, int n_in,
                              void* d_out, int out_size, void* d_ws, size_t ws_size,
                              hipStream_t stream)
{
    (void)in_sizes; (void)n_in; (void)out_size;
    const float* x   = (const float*)d_in[0];
    const float* Wih = (const float*)d_in[1];
    const float* Whh = (const float*)d_in[2];
    const float* bih = (const float*)d_in[3];
    const float* bhh = (const float*)d_in[4];
    const float* h0  = (const float*)d_in[5];
    const float* c0  = (const float*)d_in[6];
    float* out  = (float*)d_out;
    float* hbuf = (float*)d_ws;

    const size_t xt_bytes = (size_t)T_ * B_ * I_ * sizeof(_Float16);
    _Float16* xT = nullptr;
    if (ws_size >= WS_XT_OFF + xt_bytes)
        xT = (_Float16*)((char*)d_ws + WS_XT_OFF);

    // zero hbuf every launch: stale tags from a previous replay must not validate
    hipMemsetAsync(d_ws, 0, 2 * BH_ * sizeof(float), stream);
    if (xT)
        transpose_x<<<dim3(T_ / 32, I_ / 32, B_), dim3(32, 8), 0, stream>>>(x, xT);

    void* args[] = { (void*)&x, (void*)&xT, (void*)&Wih, (void*)&Whh, (void*)&bih,
                     (void*)&bhh, (void*)&h0, (void*)&c0, (void*)&out, (void*)&hbuf };
    hipLaunchCooperativeKernel((void*)lstm_fused, dim3(256), dim3(512), args, 0, stream);
}